// Round 11
// baseline (1766.524 us; speedup 1.0000x reference)
//
#include <hip/hip_runtime.h>
#include <hip/hip_fp16.h>

#define B_N 65536
#define K_N 256
#define D_N 128
#define N_ITER 50
#define NSHARD 16
#define NBLK 256                  // persist grid: 256 blocks x 1024 threads
#define BUFSTRIDE (NSHARD * K_N)  // 4096 floats per colsum buffer (16 shards x 256)
#define EVPAD 20                  // ev_lds stride: 20 floats per 16-col chunk -> 2-way banks

#define BAR_U (64 * 16)   // 1024 uints: 64 lines x 4 slots (block b -> line b&63, word b>>6)
#define P1_ITERS 400      // probe sizes chosen so both probes land in rocprof top-5
#define P2_ITERS 300

constexpr float MU_EPS = 1.0f / 65536.0f + 1e-8f;  // exp(log_mu)
constexpr float NU_EPS = 1.0f / 256.0f + 1e-8f;    // exp(log_nu)
constexpr float KSCALE = 8192.0f;                  // kept for arithmetic identity w/ verified path
constexpr float INV_KSCALE = 1.0f / 8192.0f;
constexpr float NUKS = NU_EPS * KSCALE;
constexpr float MUKS = MU_EPS * KSCALE;

typedef __attribute__((ext_vector_type(8))) short bf16x8;
typedef __attribute__((ext_vector_type(4))) float f32x4;
typedef __attribute__((ext_vector_type(4))) unsigned u32x4;

union frag_u { uint4 u; bf16x8 v; };

__device__ __forceinline__ float wave_sum(float v) {
#pragma unroll
    for (int m = 1; m < 64; m <<= 1) v += __shfl_xor(v, m, 64);
    return v;
}

// round-to-nearest-even fp32 -> bf16 bit pattern (as short)
__device__ __forceinline__ short f32_to_bf16(float x) {
    unsigned u = __float_as_uint(x);
    return (short)((u + 0x7FFFu + ((u >> 16) & 1u)) >> 16);
}
__device__ __forceinline__ float bf16_hi_f32(float x) {  // value of bf16(x)
    unsigned u = __float_as_uint(x);
    unsigned r = ((u + 0x7FFFu + ((u >> 16) & 1u)) >> 16) << 16;
    return __uint_as_float(r);
}

// ---------------------------------------------------------------------------
// Blocks 0..255: L2-normalize prototype rows; emit split-bf16 hi/lo planes in
// fragment-swizzled order (off(col,k) = ((CT*4+ks)*64 + q*16+m)*8 + j).
// Block 256: zero ALL barrier regions (real + 2 probe regions), init real
// colsum buffers AND the probe colsum region, zero d_out (harness poisons).
// ---------------------------------------------------------------------------
__global__ __launch_bounds__(64) void proto_norm_init(
        const float* __restrict__ proto, short* __restrict__ bh_s,
        short* __restrict__ bl_s, float* __restrict__ csbuf,
        unsigned* __restrict__ bar, unsigned* __restrict__ bar1,
        unsigned* __restrict__ bar2, float* __restrict__ cs2,
        float* __restrict__ out) {
    const int blk = blockIdx.x;
    const int lane = threadIdx.x;
    if (blk < 256) {
        float2 p = *(const float2*)&proto[blk * 128 + lane * 2];
        float ss = wave_sum(p.x * p.x + p.y * p.y);
        float inv = 1.0f / fmaxf(sqrtf(ss), 1e-12f);
        float v0 = p.x * inv, v1 = p.y * inv;
        short2 h, l;
        h.x = f32_to_bf16(v0); h.y = f32_to_bf16(v1);
        l.x = f32_to_bf16(v0 - bf16_hi_f32(v0));
        l.y = f32_to_bf16(v1 - bf16_hi_f32(v1));
        const int k0 = lane * 2;
        const int ks = k0 >> 5, qq = (k0 >> 3) & 3, j = k0 & 7;
        const int mm = blk & 15, CT = blk >> 4;
        const size_t off = (size_t)(((CT * 4 + ks) * 64 + qq * 16 + mm)) * 8 + j;
        *(short2*)&bh_s[off] = h;
        *(short2*)&bl_s[off] = l;
    } else {
        for (int i = lane; i < BAR_U; i += 64) { bar[i] = 0u; bar1[i] = 0u; bar2[i] = 0u; }
        for (int i = lane; i < 3 * BUFSTRIDE; i += 64) {
            csbuf[i] = (i >= 2 * BUFSTRIDE && i < 2 * BUFSTRIDE + K_N) ? NUKS : 0.0f;
            cs2[i] = 0.0f;
        }
        if (lane == 0) out[0] = 0.0f;
    }
}

// ---------------------------------------------------------------------------
// PROBE 1: pure barrier loop (arrival store + 64-line poll + 2 syncthreads).
// Measures the barrier + straggler-jitter floor per iteration. 400 iters so
// its dispatch duration exceeds the real persist and lands in rocprof top-5.
// ---------------------------------------------------------------------------
__global__ __launch_bounds__(1024, 4) void probe_bar(unsigned* __restrict__ bar1) {
    const int blk = blockIdx.x, tid = threadIdx.x;
    const int w = tid >> 6, lane = tid & 63;
    bool dead = false;
    for (int t = 0; t < P1_ITERS; t++) {
        __syncthreads();
        if (tid == 0)
            __hip_atomic_store(&bar1[(blk & 63) * 16 + (blk >> 6)], (unsigned)(t + 1),
                               __ATOMIC_RELAXED, __HIP_MEMORY_SCOPE_AGENT);
        if (w == 0 && !dead) {
            const unsigned T = (unsigned)(t + 1);
            const unsigned* ap = &bar1[lane * 16];
            long long t0 = __builtin_amdgcn_s_memrealtime();
            while (true) {
                u32x4 v;
                asm volatile("global_load_dwordx4 %0, %1, off sc0 sc1\n\t"
                             "s_waitcnt vmcnt(0)"
                             : "=v"(v) : "v"(ap) : "memory");
                if (__all(v.x >= T && v.y >= T && v.z >= T && v.w >= T)) break;
                __builtin_amdgcn_s_sleep(2);
                if (__builtin_amdgcn_s_memrealtime() - t0 > (1LL << 18)) {
                    dead = true;  // ~2.6 ms probe timeout: bail fast, never hang
                    break;
                }
            }
        }
        __syncthreads();
    }
}

// ---------------------------------------------------------------------------
// PROBE 2: barrier + the REAL colsum exchange phases (16 shard reads, zero
// store, 256 atomicAdds, same 4-syncthreads skeleton) with the row compute
// removed (read result kept alive via asm — avoids DCE of the loads).
// P2/300 - P1/400 isolates the colsum drain+read cost per iteration.
// ---------------------------------------------------------------------------
__global__ __launch_bounds__(1024, 4) void probe_colsum(
        float* __restrict__ cs2, unsigned* __restrict__ bar2) {
    const int blk = blockIdx.x, tid = threadIdx.x;
    const int w = tid >> 6, lane = tid & 63;
    bool dead = false;
    for (int t = 0; t < P2_ITERS; t++) {
        const int p_read = (t + 2) % 3, p_acc = t % 3, p_zero = (t + 1) % 3;
        float cs = 0.0f;
        if (tid < 256) {
            const float* cb = cs2 + p_read * BUFSTRIDE;
#pragma unroll
            for (int s = 0; s < NSHARD; s++)
                cs += __hip_atomic_load(&cb[s * 256 + tid], __ATOMIC_RELAXED,
                                        __HIP_MEMORY_SCOPE_AGENT);
        }
        asm volatile("" :: "v"(cs));   // keep the reads live (rule: no DCE-by-skip)
        if (blk < NSHARD && tid < 256)
            __hip_atomic_store(&cs2[p_zero * BUFSTRIDE + blk * 256 + tid], 0.0f,
                               __ATOMIC_RELAXED, __HIP_MEMORY_SCOPE_AGENT);
        __syncthreads();
        // (row compute skipped)
        __syncthreads();
        if (tid < 256)
            atomicAdd(&cs2[p_acc * BUFSTRIDE + (blk & (NSHARD - 1)) * 256 + tid], 1.0f);
        __syncthreads();
        if (tid == 0)
            __hip_atomic_store(&bar2[(blk & 63) * 16 + (blk >> 6)], (unsigned)(t + 1),
                               __ATOMIC_RELAXED, __HIP_MEMORY_SCOPE_AGENT);
        if (w == 0 && !dead) {
            const unsigned T = (unsigned)(t + 1);
            const unsigned* ap = &bar2[lane * 16];
            long long t0 = __builtin_amdgcn_s_memrealtime();
            while (true) {
                u32x4 v;
                asm volatile("global_load_dwordx4 %0, %1, off sc0 sc1\n\t"
                             "s_waitcnt vmcnt(0)"
                             : "=v"(v) : "v"(ap) : "memory");
                if (__all(v.x >= T && v.y >= T && v.z >= T && v.w >= T)) break;
                __builtin_amdgcn_s_sleep(2);
                if (__builtin_amdgcn_s_memrealtime() - t0 > (1LL << 18)) {
                    dead = true;
                    break;
                }
            }
        }
        __syncthreads();
    }
}

// ---------------------------------------------------------------------------
// FULLY-FUSED PERSISTENT kernel — UNCHANGED from round 10 (clean replicate).
// ---------------------------------------------------------------------------
__global__ __launch_bounds__(1024, 4) void sinkhorn_persist(
        const float* __restrict__ x, const short* __restrict__ bh_s,
        const short* __restrict__ bl_s, float* __restrict__ csbuf,
        const float* __restrict__ coord, unsigned* __restrict__ bar,
        float* __restrict__ out) {
    __shared__ __align__(16) float ev_lds[16 * EVPAD];  // [chunk][idx] stride-20
    __shared__ float cs_lds[16 * 273];  // [wave][chunk*17 + idx] stride-17
    __shared__ float wpart[16];
    const int blk = blockIdx.x, tid = threadIdx.x;
    const int w = tid >> 6, lane = tid & 63;
    const int q = lane >> 4, m = lane & 15;

    // ---- phase 0: fused split-bf16 MFMA GEMM + row-norm, kappa -> registers ----
    const int arow = blk * 256 + w * 16 + m;   // A-tile row for this lane
    float av[4][8];
    float ss = 0.0f;
#pragma unroll
    for (int ks = 0; ks < 4; ks++) {
        const float* ap = &x[(size_t)arow * 128 + ks * 32 + q * 8];
        float4 a0 = *(const float4*)ap;
        float4 a1 = *(const float4*)(ap + 4);
        av[ks][0] = a0.x; av[ks][1] = a0.y; av[ks][2] = a0.z; av[ks][3] = a0.w;
        av[ks][4] = a1.x; av[ks][5] = a1.y; av[ks][6] = a1.z; av[ks][7] = a1.w;
#pragma unroll
        for (int j = 0; j < 8; j++) ss = fmaf(av[ks][j], av[ks][j], ss);
    }
    ss += __shfl_xor(ss, 16, 64);   // row m's 4 k-chunks live at lanes {m,m+16,m+32,m+48}
    ss += __shfl_xor(ss, 32, 64);
    const float rnv = 1.0f / fmaxf(sqrtf(ss), 1e-12f);
    frag_u ah[4], al[4];
#pragma unroll
    for (int ks = 0; ks < 4; ks++) {
        unsigned uh[4], ul[4];
#pragma unroll
        for (int p = 0; p < 4; p++) {
            float a0 = av[ks][2 * p] * rnv;
            float a1 = av[ks][2 * p + 1] * rnv;
            unsigned u;
            asm("v_cvt_pk_bf16_f32 %0, %1, %2" : "=v"(u) : "v"(a0), "v"(a1));
            float h0 = __uint_as_float(u << 16);
            float h1 = __uint_as_float(u & 0xffff0000u);
            float l0 = a0 - h0, l1 = a1 - h1;
            unsigned u2;
            asm("v_cvt_pk_bf16_f32 %0, %1, %2" : "=v"(u2) : "v"(l0), "v"(l1));
            uh[p] = u; ul[p] = u2;
        }
        ah[ks].u = make_uint4(uh[0], uh[1], uh[2], uh[3]);
        al[ks].u = make_uint4(ul[0], ul[1], ul[2], ul[3]);
    }
    float kvf[4][16];   // kvf[r][CT]: kappa(row w*16+q*4+r, col CT*16+m), f32
    {
        f32x4 acc[16];
#pragma unroll
        for (int CT = 0; CT < 16; CT++) acc[CT] = (f32x4){0.f, 0.f, 0.f, 0.f};
#pragma unroll
        for (int ks = 0; ks < 4; ks++) {
#pragma unroll
            for (int CT = 0; CT < 16; CT++) {
                const size_t off = (size_t)(((CT * 4 + ks) * 64 + lane)) * 8;
                bf16x8 bh = *(const bf16x8*)&bh_s[off];
                bf16x8 bl = *(const bf16x8*)&bl_s[off];
                acc[CT] = __builtin_amdgcn_mfma_f32_16x16x32_bf16(ah[ks].v, bh, acc[CT], 0, 0, 0);
                acc[CT] = __builtin_amdgcn_mfma_f32_16x16x32_bf16(al[ks].v, bh, acc[CT], 0, 0, 0);
                acc[CT] = __builtin_amdgcn_mfma_f32_16x16x32_bf16(ah[ks].v, bl, acc[CT], 0, 0, 0);
            }
        }
#pragma unroll
        for (int CT = 0; CT < 16; CT++) {
#pragma unroll
            for (int r = 0; r < 4; r++) {
                float Cv = 1.0f - acc[CT][r];
                kvf[r][CT] = KSCALE * (__expf(-10.0f * Cv) + 1e-8f);
            }
        }
    }

    // ---- phase 1: 50 Sinkhorn iterations ----
    float ai_reg[4] = {0.f, 0.f, 0.f, 0.f};
    bool dead = false;
    for (int t = 0; t < N_ITER; t++) {
        const int p_read = (t + 2) % 3, p_acc = t % 3, p_zero = (t + 1) % 3;
        if (tid < 256) {  // ev_k = NUKS / colsum_k (thread tid owns column tid)
            const float* cb = csbuf + p_read * BUFSTRIDE;
            float cs = 0.0f;
#pragma unroll
            for (int s = 0; s < NSHARD; s++)
                cs += __hip_atomic_load(&cb[s * 256 + tid], __ATOMIC_RELAXED,
                                        __HIP_MEMORY_SCOPE_AGENT);
            ev_lds[(tid >> 4) * EVPAD + (tid & 15)] = NUKS * __builtin_amdgcn_rcpf(cs);
        }
        if (blk < NSHARD && tid < 256)
            __hip_atomic_store(&csbuf[p_zero * BUFSTRIDE + blk * 256 + tid], 0.0f,
                               __ATOMIC_RELAXED, __HIP_MEMORY_SCOPE_AGENT);
        __syncthreads();
        float e[16];   // e[j] = ev[col j*16+m]
#pragma unroll
        for (int j = 0; j < 16; j++) e[j] = ev_lds[j * EVPAD + m];
        float acc[16];
#pragma unroll
        for (int j = 0; j < 16; j++) acc[j] = 0.0f;
#pragma unroll
        for (int rg = 0; rg < 4; rg++) {
            float part = 0.0f;
#pragma unroll
            for (int j = 0; j < 16; j++) part = fmaf(kvf[rg][j], e[j], part);
            part += __shfl_xor(part, 8, 64);   // reduce over the 16 m-lanes
            part += __shfl_xor(part, 4, 64);
            part += __shfl_xor(part, 2, 64);
            part += __shfl_xor(part, 1, 64);
            float ai = MUKS * __builtin_amdgcn_rcpf(part);  // = exp(u_row)
            ai_reg[rg] = ai;
#pragma unroll
            for (int j = 0; j < 16; j++) acc[j] = fmaf(kvf[rg][j], ai, acc[j]);
        }
#pragma unroll
        for (int j = 0; j < 16; j++) {   // reduce over q (the wave's 16 rows)
            acc[j] += __shfl_xor(acc[j], 16, 64);
            acc[j] += __shfl_xor(acc[j], 32, 64);
        }
        if (q == 0) {  // lanes m=0..15 hold colsum for cols j*16+m
#pragma unroll
            for (int j = 0; j < 16; j++) cs_lds[w * 273 + j * 17 + m] = acc[j];
        }
        __syncthreads();
        if (tid < 256) {
            float v = 0.0f;
#pragma unroll
            for (int p = 0; p < 16; p++) v += cs_lds[p * 273 + (tid >> 4) * 17 + (tid & 15)];
            atomicAdd(&csbuf[p_acc * BUFSTRIDE + (blk & (NSHARD - 1)) * 256 + tid], v);
        }
        // ---- single-hop store-only barrier ----
        __syncthreads();   // each wave drains its vmcnt: payload at coherent point
        if (tid == 0)
            __hip_atomic_store(&bar[(blk & 63) * 16 + (blk >> 6)], (unsigned)(t + 1),
                               __ATOMIC_RELAXED, __HIP_MEMORY_SCOPE_AGENT);
        if (w == 0 && !dead) {
            const unsigned T = (unsigned)(t + 1);
            const unsigned* ap = &bar[lane * 16];  // lane i polls line i, words 0..3
            long long t0 = __builtin_amdgcn_s_memrealtime();
            while (true) {
                u32x4 v;
                asm volatile("global_load_dwordx4 %0, %1, off sc0 sc1\n\t"
                             "s_waitcnt vmcnt(0)"
                             : "=v"(v) : "v"(ap) : "memory");
                if (__all(v.x >= T && v.y >= T && v.z >= T && v.w >= T)) break;
                __builtin_amdgcn_s_sleep(2);
                if (__builtin_amdgcn_s_memrealtime() - t0 > (1LL << 22)) {
                    dead = true;  // ~42 ms: co-residency violated; bail, no hang
                    break;
                }
            }
        }
        __syncthreads();
    }

    // ---- phase 2: finalize (kappa + ai in registers) ----
    if (tid < 256) {
        const float* cb = csbuf + ((N_ITER - 1) % 3) * BUFSTRIDE;  // p_acc of t=49
        float cs = 0.0f;
#pragma unroll
        for (int s = 0; s < NSHARD; s++)
            cs += __hip_atomic_load(&cb[s * 256 + tid], __ATOMIC_RELAXED,
                                    __HIP_MEMORY_SCOPE_AGENT);
        ev_lds[(tid >> 4) * EVPAD + (tid & 15)] = NUKS * __builtin_amdgcn_rcpf(cs);
    }
    __syncthreads();
    float ef[16];
#pragma unroll
    for (int j = 0; j < 16; j++) ef[j] = ev_lds[j * EVPAD + m];
    float accv = 0.0f;
#pragma unroll
    for (int rg = 0; rg < 4; rg++) {
        const int row = blk * 256 + w * 16 + q * 4 + rg;
        float a[16];
#pragma unroll
        for (int j = 0; j < 16; j++)
            a[j] = fabsf(coord[(size_t)row * 256 + j * 16 + m]);
        float mx = a[0];
#pragma unroll
        for (int j = 1; j < 16; j++) mx = fmaxf(mx, a[j]);
        mx = fmaxf(mx, __shfl_xor(mx, 8, 64));   // row spans the 16 m-lanes
        mx = fmaxf(mx, __shfl_xor(mx, 4, 64));
        mx = fmaxf(mx, __shfl_xor(mx, 2, 64));
        mx = fmaxf(mx, __shfl_xor(mx, 1, 64));
        float ex[16];
        float zs = 0.0f;
#pragma unroll
        for (int j = 0; j < 16; j++) { ex[j] = __expf(a[j] - mx); zs += ex[j]; }
        zs += __shfl_xor(zs, 8, 64);
        zs += __shfl_xor(zs, 4, 64);
        zs += __shfl_xor(zs, 2, 64);
        zs += __shfl_xor(zs, 1, 64);
        float s = 0.0f;
#pragma unroll
        for (int j = 0; j < 16; j++) {
            float Cj = -0.1f * __logf(kvf[rg][j] * INV_KSCALE - 1e-8f);
            s += kvf[rg][j] * ef[j] * Cj * ex[j];
        }
        accv = fmaf(s, ai_reg[rg] * INV_KSCALE * __builtin_amdgcn_rcpf(zs), accv);
    }
    accv = wave_sum(accv);
    if (lane == 0) wpart[w] = accv;
    __syncthreads();
    if (tid == 0) {
        float tot = 0.0f;
#pragma unroll
        for (int i = 0; i < 16; i++) tot += wpart[i];
        atomicAdd(out, tot);
    }
}

extern "C" void kernel_launch(void* const* d_in, const int* in_sizes, int n_in,
                              void* d_out, int out_size, void* d_ws, size_t ws_size,
                              hipStream_t stream) {
    const float* x = (const float*)d_in[0];
    const float* proto = (const float*)d_in[1];
    const float* coord = (const float*)d_in[2];
    float* out = (float*)d_out;
    char* ws = (char*)d_ws;
    // workspace layout: probe regions live in the freed 32MB ex-kappa slot
    unsigned* bar1 = (unsigned*)(ws);                       // 4 KB (probe 1 barrier)
    unsigned* bar2 = (unsigned*)(ws + 8192);                // 4 KB (probe 2 barrier)
    float* cs2 = (float*)(ws + 16384);                      // 48 KB (probe 2 colsums)
    short* bh_s = (short*)(ws + 33554432);                  // 64 KB (swizzled hi plane)
    short* bl_s = bh_s + 32768;                             // 64 KB (swizzled lo plane)
    unsigned* bar = (unsigned*)(ws + 33554432 + 131072 + 262144);       // 4 KB barrier slots
    float* csbuf = (float*)(ws + 33554432 + 131072 + 262144 + 262144);  // 48 KB

    hipLaunchKernelGGL(proto_norm_init, dim3(257), dim3(64), 0, stream,
                       proto, bh_s, bl_s, csbuf, bar, bar1, bar2, cs2, out);
    hipLaunchKernelGGL(probe_bar, dim3(NBLK), dim3(1024), 0, stream, bar1);
    hipLaunchKernelGGL(probe_colsum, dim3(NBLK), dim3(1024), 0, stream, cs2, bar2);
    hipLaunchKernelGGL(sinkhorn_persist, dim3(NBLK), dim3(1024), 0, stream,
                       x, bh_s, bl_s, csbuf, coord, bar, out);
}

// Round 12
// 350.338 us; speedup vs baseline: 5.0423x; 5.0423x over previous
//
#include <hip/hip_runtime.h>
#include <hip/hip_fp16.h>

#define B_N 65536
#define K_N 256
#define D_N 128
#define N_ITER 50
#define NSHARD 16
#define NBLK 256                  // persist grid: 256 blocks x 1024 threads
#define BUFSTRIDE (NSHARD * K_N)  // 4096 floats per colsum buffer (16 shards x 256)
#define EVPAD 20                  // ev_lds [m][j] stride-20: 2-way banks (free), 16B-aligned rows
#define CS2_STRIDE 68             // cs_lds [col][slot] stride-68: writer 2-way banks, 16B-aligned

#define BAR_U (64 * 16)   // 1024 uints: 64 lines x 4 slots (block b -> line b&63, word b>>6)

constexpr float MU_EPS = 1.0f / 65536.0f + 1e-8f;  // exp(log_mu)
constexpr float NU_EPS = 1.0f / 256.0f + 1e-8f;    // exp(log_nu)
constexpr float KSCALE = 8192.0f;                  // kept for arithmetic identity w/ verified path
constexpr float INV_KSCALE = 1.0f / 8192.0f;
constexpr float NUKS = NU_EPS * KSCALE;
constexpr float MUKS = MU_EPS * KSCALE;

typedef __attribute__((ext_vector_type(8))) short bf16x8;
typedef __attribute__((ext_vector_type(4))) float f32x4;
typedef __attribute__((ext_vector_type(4))) unsigned u32x4;

union frag_u { uint4 u; bf16x8 v; };

__device__ __forceinline__ float wave_sum(float v) {
#pragma unroll
    for (int m = 1; m < 64; m <<= 1) v += __shfl_xor(v, m, 64);
    return v;
}

// 16-lane butterfly sum on the VALU pipe (DPP), no LDS traffic.
// quad_perm[1,0,3,2]=0xB1 (xor1), quad_perm[2,3,0,1]=0x4E (xor2),
// row_half_mirror=0x141 (combines quads), row_mirror=0x140 (combines octets).
__device__ __forceinline__ float dpp_sum16(float v) {
    int x;
    x = __builtin_amdgcn_update_dpp(0, __float_as_int(v), 0xB1, 0xF, 0xF, true);
    v += __int_as_float(x);
    x = __builtin_amdgcn_update_dpp(0, __float_as_int(v), 0x4E, 0xF, 0xF, true);
    v += __int_as_float(x);
    x = __builtin_amdgcn_update_dpp(0, __float_as_int(v), 0x141, 0xF, 0xF, true);
    v += __int_as_float(x);
    x = __builtin_amdgcn_update_dpp(0, __float_as_int(v), 0x140, 0xF, 0xF, true);
    v += __int_as_float(x);
    return v;
}

// round-to-nearest-even fp32 -> bf16 bit pattern (as short)
__device__ __forceinline__ short f32_to_bf16(float x) {
    unsigned u = __float_as_uint(x);
    return (short)((u + 0x7FFFu + ((u >> 16) & 1u)) >> 16);
}
__device__ __forceinline__ float bf16_hi_f32(float x) {  // value of bf16(x)
    unsigned u = __float_as_uint(x);
    unsigned r = ((u + 0x7FFFu + ((u >> 16) & 1u)) >> 16) << 16;
    return __uint_as_float(r);
}

// ---------------------------------------------------------------------------
// Blocks 0..255: L2-normalize prototype rows; emit split-bf16 hi/lo planes in
// fragment-swizzled order (off(col,k) = ((CT*4+ks)*64 + q*16+m)*8 + j).
// Block 256: zero the 1KB barrier slots, init colsum buffers (3-buffer
// rotation; buf2/shard0 = NUKS so iteration 0 sees exp(v)=1), zero d_out.
// ---------------------------------------------------------------------------
__global__ __launch_bounds__(64) void proto_norm_init(
        const float* __restrict__ proto, short* __restrict__ bh_s,
        short* __restrict__ bl_s, float* __restrict__ csbuf,
        unsigned* __restrict__ bar, float* __restrict__ out) {
    const int blk = blockIdx.x;
    const int lane = threadIdx.x;
    if (blk < 256) {
        float2 p = *(const float2*)&proto[blk * 128 + lane * 2];
        float ss = wave_sum(p.x * p.x + p.y * p.y);
        float inv = 1.0f / fmaxf(sqrtf(ss), 1e-12f);
        float v0 = p.x * inv, v1 = p.y * inv;
        short2 h, l;
        h.x = f32_to_bf16(v0); h.y = f32_to_bf16(v1);
        l.x = f32_to_bf16(v0 - bf16_hi_f32(v0));
        l.y = f32_to_bf16(v1 - bf16_hi_f32(v1));
        const int k0 = lane * 2;
        const int ks = k0 >> 5, qq = (k0 >> 3) & 3, j = k0 & 7;
        const int mm = blk & 15, CT = blk >> 4;
        const size_t off = (size_t)(((CT * 4 + ks) * 64 + qq * 16 + mm)) * 8 + j;
        *(short2*)&bh_s[off] = h;
        *(short2*)&bl_s[off] = l;
    } else {
        for (int i = lane; i < BAR_U; i += 64) bar[i] = 0u;
        for (int i = lane; i < 3 * BUFSTRIDE; i += 64)
            csbuf[i] = (i >= 2 * BUFSTRIDE && i < 2 * BUFSTRIDE + K_N) ? NUKS : 0.0f;
        if (lane == 0) out[0] = 0.0f;
    }
}

// ---------------------------------------------------------------------------
// FULLY-FUSED PERSISTENT kernel: in-register GEMM + 50 Sinkhorn iters + final.
// Round-12 compute restructure (probe-driven: barrier=1.71us, exchange<=0.6,
// compute~3.6us/iter was LDS-pipe-bound at ~1350 LDS wave-instrs/iter):
//  - part-reduce: DPP butterfly on VALU (was 256 ds_bpermute/CU/iter)
//  - acc-reduce: ELIMINATED — every lane writes its 16 raw q-partials to
//    cs_lds[col][slot=w*4+q] (stride-68: 2-way banks, free); the 256 colsum
//    threads read 64 contiguous floats as 16x float4 (was 512 ds_bpermute +
//    scalar reads)
//  - ev transposed to [m][j] stride-20: 4x float4 per thread, broadcast
//    across q (was 16 scalar ds_read)
// ~390 LDS wave-instrs/iter remain. Barrier: round-10 single-hop store-only
// (arrival store of t+1 to own slot; wave 0 polls 64 lines via
// global_load_dwordx4 sc0 sc1 + __all; lesson chain: acquire-spin=inval
// storm r2; single-counter RMW serialization r3; polled lines must not be
// RMW'd r8). Payload = IC-point atomics; __syncthreads drains vmcnt before
// arrival. Sticky ~42ms timeout bails instead of hanging.
// ---------------------------------------------------------------------------
__global__ __launch_bounds__(1024, 4) void sinkhorn_persist(
        const float* __restrict__ x, const short* __restrict__ bh_s,
        const short* __restrict__ bl_s, float* __restrict__ csbuf,
        const float* __restrict__ coord, unsigned* __restrict__ bar,
        float* __restrict__ out) {
    __shared__ __align__(16) float ev_lds[16 * EVPAD];        // [m][j] stride-20
    __shared__ __align__(16) float cs_lds[256 * CS2_STRIDE];  // [col][slot] stride-68 (~70KB)
    __shared__ float wpart[16];
    const int blk = blockIdx.x, tid = threadIdx.x;
    const int w = tid >> 6, lane = tid & 63;
    const int q = lane >> 4, m = lane & 15;

    // ---- phase 0: fused split-bf16 MFMA GEMM + row-norm, kappa -> registers ----
    const int arow = blk * 256 + w * 16 + m;   // A-tile row for this lane
    float av[4][8];
    float ss = 0.0f;
#pragma unroll
    for (int ks = 0; ks < 4; ks++) {
        const float* ap = &x[(size_t)arow * 128 + ks * 32 + q * 8];
        float4 a0 = *(const float4*)ap;
        float4 a1 = *(const float4*)(ap + 4);
        av[ks][0] = a0.x; av[ks][1] = a0.y; av[ks][2] = a0.z; av[ks][3] = a0.w;
        av[ks][4] = a1.x; av[ks][5] = a1.y; av[ks][6] = a1.z; av[ks][7] = a1.w;
#pragma unroll
        for (int j = 0; j < 8; j++) ss = fmaf(av[ks][j], av[ks][j], ss);
    }
    ss += __shfl_xor(ss, 16, 64);   // row m's 4 k-chunks live at lanes {m,m+16,m+32,m+48}
    ss += __shfl_xor(ss, 32, 64);
    const float rnv = 1.0f / fmaxf(sqrtf(ss), 1e-12f);
    frag_u ah[4], al[4];
#pragma unroll
    for (int ks = 0; ks < 4; ks++) {
        unsigned uh[4], ul[4];
#pragma unroll
        for (int p = 0; p < 4; p++) {
            float a0 = av[ks][2 * p] * rnv;
            float a1 = av[ks][2 * p + 1] * rnv;
            unsigned u;
            asm("v_cvt_pk_bf16_f32 %0, %1, %2" : "=v"(u) : "v"(a0), "v"(a1));
            float h0 = __uint_as_float(u << 16);
            float h1 = __uint_as_float(u & 0xffff0000u);
            float l0 = a0 - h0, l1 = a1 - h1;
            unsigned u2;
            asm("v_cvt_pk_bf16_f32 %0, %1, %2" : "=v"(u2) : "v"(l0), "v"(l1));
            uh[p] = u; ul[p] = u2;
        }
        ah[ks].u = make_uint4(uh[0], uh[1], uh[2], uh[3]);
        al[ks].u = make_uint4(ul[0], ul[1], ul[2], ul[3]);
    }
    float kvf[4][16];   // kvf[r][CT]: kappa(row w*16+q*4+r, col CT*16+m), f32
    {
        f32x4 acc[16];
#pragma unroll
        for (int CT = 0; CT < 16; CT++) acc[CT] = (f32x4){0.f, 0.f, 0.f, 0.f};
#pragma unroll
        for (int ks = 0; ks < 4; ks++) {
#pragma unroll
            for (int CT = 0; CT < 16; CT++) {
                const size_t off = (size_t)(((CT * 4 + ks) * 64 + lane)) * 8;
                bf16x8 bh = *(const bf16x8*)&bh_s[off];
                bf16x8 bl = *(const bf16x8*)&bl_s[off];
                acc[CT] = __builtin_amdgcn_mfma_f32_16x16x32_bf16(ah[ks].v, bh, acc[CT], 0, 0, 0);
                acc[CT] = __builtin_amdgcn_mfma_f32_16x16x32_bf16(al[ks].v, bh, acc[CT], 0, 0, 0);
                acc[CT] = __builtin_amdgcn_mfma_f32_16x16x32_bf16(ah[ks].v, bl, acc[CT], 0, 0, 0);
            }
        }
#pragma unroll
        for (int CT = 0; CT < 16; CT++) {
#pragma unroll
            for (int r = 0; r < 4; r++) {
                float Cv = 1.0f - acc[CT][r];
                kvf[r][CT] = KSCALE * (__expf(-10.0f * Cv) + 1e-8f);
            }
        }
    }

    // ---- phase 1: 50 Sinkhorn iterations ----
    float ai_reg[4] = {0.f, 0.f, 0.f, 0.f};
    bool dead = false;
    for (int t = 0; t < N_ITER; t++) {
        const int p_read = (t + 2) % 3, p_acc = t % 3, p_zero = (t + 1) % 3;
        if (tid < 256) {  // ev for column tid -> ev_lds[m'][j'] = [(tid&15)*20 + (tid>>4)]
            const float* cb = csbuf + p_read * BUFSTRIDE;
            float cs = 0.0f;
#pragma unroll
            for (int s = 0; s < NSHARD; s++)
                cs += __hip_atomic_load(&cb[s * 256 + tid], __ATOMIC_RELAXED,
                                        __HIP_MEMORY_SCOPE_AGENT);
            ev_lds[(tid & 15) * EVPAD + (tid >> 4)] = NUKS * __builtin_amdgcn_rcpf(cs);
        }
        if (blk < NSHARD && tid < 256)
            __hip_atomic_store(&csbuf[p_zero * BUFSTRIDE + blk * 256 + tid], 0.0f,
                               __ATOMIC_RELAXED, __HIP_MEMORY_SCOPE_AGENT);
        __syncthreads();
        float e[16];   // e[j] = ev[col j*16+m] — 4x float4, broadcast across q
        {
            const float4* ep = (const float4*)(ev_lds + m * EVPAD);
            float4 E0 = ep[0], E1 = ep[1], E2 = ep[2], E3 = ep[3];
            e[0] = E0.x; e[1] = E0.y; e[2] = E0.z; e[3] = E0.w;
            e[4] = E1.x; e[5] = E1.y; e[6] = E1.z; e[7] = E1.w;
            e[8] = E2.x; e[9] = E2.y; e[10] = E2.z; e[11] = E2.w;
            e[12] = E3.x; e[13] = E3.y; e[14] = E3.z; e[15] = E3.w;
        }
        float acc[16];
#pragma unroll
        for (int j = 0; j < 16; j++) acc[j] = 0.0f;
#pragma unroll
        for (int rg = 0; rg < 4; rg++) {
            float part = 0.0f;
#pragma unroll
            for (int j = 0; j < 16; j++) part = fmaf(kvf[rg][j], e[j], part);
            part = dpp_sum16(part);                         // 16-lane sum on VALU pipe
            float ai = MUKS * __builtin_amdgcn_rcpf(part);  // = exp(u_row)
            ai_reg[rg] = ai;
#pragma unroll
            for (int j = 0; j < 16; j++) acc[j] = fmaf(kvf[rg][j], ai, acc[j]);
        }
        // acc-reduce over (w,q) moved to LDS: every lane writes raw partials
        const int slot = w * 4 + q;
#pragma unroll
        for (int j = 0; j < 16; j++)
            cs_lds[(j * 16 + m) * CS2_STRIDE + slot] = acc[j];
        __syncthreads();
        if (tid < 256) {  // col tid: sum 64 partials (16x float4, contiguous)
            const float4* rp = (const float4*)(cs_lds + tid * CS2_STRIDE);
            float v = 0.0f;
#pragma unroll
            for (int s4 = 0; s4 < 16; s4++) {
                float4 s = rp[s4];
                v += s.x + s.y + s.z + s.w;
            }
            atomicAdd(&csbuf[p_acc * BUFSTRIDE + (blk & (NSHARD - 1)) * 256 + tid], v);
        }
        // ---- single-hop store-only barrier ----
        __syncthreads();   // each wave drains its vmcnt: payload at coherent point
        if (tid == 0)
            __hip_atomic_store(&bar[(blk & 63) * 16 + (blk >> 6)], (unsigned)(t + 1),
                               __ATOMIC_RELAXED, __HIP_MEMORY_SCOPE_AGENT);
        if (w == 0 && !dead) {
            const unsigned T = (unsigned)(t + 1);
            const unsigned* ap = &bar[lane * 16];  // lane i polls line i, words 0..3
            long long t0 = __builtin_amdgcn_s_memrealtime();
            while (true) {
                u32x4 v;
                asm volatile("global_load_dwordx4 %0, %1, off sc0 sc1\n\t"
                             "s_waitcnt vmcnt(0)"
                             : "=v"(v) : "v"(ap) : "memory");
                if (__all(v.x >= T && v.y >= T && v.z >= T && v.w >= T)) break;
                __builtin_amdgcn_s_sleep(2);
                if (__builtin_amdgcn_s_memrealtime() - t0 > (1LL << 22)) {
                    dead = true;  // ~42 ms: co-residency violated; bail, no hang
                    break;
                }
            }
        }
        __syncthreads();
    }

    // ---- phase 2: finalize (kappa + ai in registers) ----
    if (tid < 256) {
        const float* cb = csbuf + ((N_ITER - 1) % 3) * BUFSTRIDE;  // p_acc of t=49
        float cs = 0.0f;
#pragma unroll
        for (int s = 0; s < NSHARD; s++)
            cs += __hip_atomic_load(&cb[s * 256 + tid], __ATOMIC_RELAXED,
                                    __HIP_MEMORY_SCOPE_AGENT);
        ev_lds[(tid & 15) * EVPAD + (tid >> 4)] = NUKS * __builtin_amdgcn_rcpf(cs);
    }
    __syncthreads();
    float ef[16];
    {
        const float4* ep = (const float4*)(ev_lds + m * EVPAD);
        float4 E0 = ep[0], E1 = ep[1], E2 = ep[2], E3 = ep[3];
        ef[0] = E0.x; ef[1] = E0.y; ef[2] = E0.z; ef[3] = E0.w;
        ef[4] = E1.x; ef[5] = E1.y; ef[6] = E1.z; ef[7] = E1.w;
        ef[8] = E2.x; ef[9] = E2.y; ef[10] = E2.z; ef[11] = E2.w;
        ef[12] = E3.x; ef[13] = E3.y; ef[14] = E3.z; ef[15] = E3.w;
    }
    float accv = 0.0f;
#pragma unroll
    for (int rg = 0; rg < 4; rg++) {
        const int row = blk * 256 + w * 16 + q * 4 + rg;
        float a[16];
#pragma unroll
        for (int j = 0; j < 16; j++)
            a[j] = fabsf(coord[(size_t)row * 256 + j * 16 + m]);
        float mx = a[0];
#pragma unroll
        for (int j = 1; j < 16; j++) mx = fmaxf(mx, a[j]);
        mx = fmaxf(mx, __shfl_xor(mx, 8, 64));   // row spans the 16 m-lanes
        mx = fmaxf(mx, __shfl_xor(mx, 4, 64));
        mx = fmaxf(mx, __shfl_xor(mx, 2, 64));
        mx = fmaxf(mx, __shfl_xor(mx, 1, 64));
        float ex[16];
        float zs = 0.0f;
#pragma unroll
        for (int j = 0; j < 16; j++) { ex[j] = __expf(a[j] - mx); zs += ex[j]; }
        zs += __shfl_xor(zs, 8, 64);
        zs += __shfl_xor(zs, 4, 64);
        zs += __shfl_xor(zs, 2, 64);
        zs += __shfl_xor(zs, 1, 64);
        float s = 0.0f;
#pragma unroll
        for (int j = 0; j < 16; j++) {
            float Cj = -0.1f * __logf(kvf[rg][j] * INV_KSCALE - 1e-8f);
            s += kvf[rg][j] * ef[j] * Cj * ex[j];
        }
        accv = fmaf(s, ai_reg[rg] * INV_KSCALE * __builtin_amdgcn_rcpf(zs), accv);
    }
    accv = wave_sum(accv);
    if (lane == 0) wpart[w] = accv;
    __syncthreads();
    if (tid == 0) {
        float tot = 0.0f;
#pragma unroll
        for (int i = 0; i < 16; i++) tot += wpart[i];
        atomicAdd(out, tot);
    }
}

extern "C" void kernel_launch(void* const* d_in, const int* in_sizes, int n_in,
                              void* d_out, int out_size, void* d_ws, size_t ws_size,
                              hipStream_t stream) {
    const float* x = (const float*)d_in[0];
    const float* proto = (const float*)d_in[1];
    const float* coord = (const float*)d_in[2];
    float* out = (float*)d_out;
    char* ws = (char*)d_ws;
    // workspace layout (offsets kept stable)
    short* bh_s = (short*)(ws + 33554432);                  // 64 KB (swizzled hi plane)
    short* bl_s = bh_s + 32768;                             // 64 KB (swizzled lo plane)
    unsigned* bar = (unsigned*)(ws + 33554432 + 131072 + 262144);       // 4 KB barrier slots
    float* csbuf = (float*)(ws + 33554432 + 131072 + 262144 + 262144);  // 48 KB

    hipLaunchKernelGGL(proto_norm_init, dim3(257), dim3(64), 0, stream,
                       proto, bh_s, bl_s, csbuf, bar, out);
    hipLaunchKernelGGL(sinkhorn_persist, dim3(NBLK), dim3(1024), 0, stream,
                       x, bh_s, bl_s, csbuf, coord, bar, out);
}